// Round 9
// baseline (308.886 us; speedup 1.0000x reference)
//
#include <hip/hip_runtime.h>
#include <hip/hip_bf16.h>

typedef __attribute__((ext_vector_type(8))) short short8;
typedef __attribute__((ext_vector_type(4))) float f32x4;
typedef __attribute__((ext_vector_type(16))) float f32x16;
typedef unsigned short u16;
typedef unsigned int u32;

// ---------------- workspace layout (bytes) ----------------
#define OFF_XT      0u          // x NHWC bf16: 4*64*64*256 = 8388608 B
#define OFF_OM      8388608u    // offsets fp32: 16384*32*4  = 2097152 B
#define OFF_Y       10485760u   // mdcn out NHWC bf16: 16384*128*2 = 4194304 B
#define OFF_Y2      14680064u   // deconv out NCHW bf16: 4*128*128*128*2 = 16777216 B
#define OFF_BOFF    31457280u   // Boff16 [72][2][64][8] bf16 = 147456 B
#define OFF_BDCN    31604736u   // Bdcn16 [72][8][64][8] bf16 = 589824 B
#define OFF_BUP     32194560u   // Bup'  [4][32][4][2][32][8] bf16 = 524288 B
#define OFF_STATS   32718848u   // stats1 sum/ss [256] + stats2 [256] f32 = 2048 B
#define OFF_BN1     32720896u   // float2[128]
#define OFF_BN2     32721920u   // float2[128]

__device__ __forceinline__ float lo2f(u32 u){ u32 v = u << 16; float f; __builtin_memcpy(&f, &v, 4); return f; }
__device__ __forceinline__ float hi2f(u32 u){ u32 v = u & 0xffff0000u; float f; __builtin_memcpy(&f, &v, 4); return f; }
__device__ __forceinline__ float b2f(u16 v){ u32 u = ((u32)v) << 16; float f; __builtin_memcpy(&f, &u, 4); return f; }
__device__ __forceinline__ u16 f2b(float f){ __hip_bfloat16 h = __float2bfloat16(f); u16 r; __builtin_memcpy(&r, &h, 2); return r; }
// fast RNE f32->bf16 (finite values only)
__device__ __forceinline__ u32 rne(float f){ u32 u; __builtin_memcpy(&u, &f, 4); return u + 0x7FFFu + ((u >> 16) & 1u); }
__device__ __forceinline__ u32 pk2(float f0, float f1){ return (rne(f0) >> 16) | (rne(f1) & 0xFFFF0000u); }

__device__ __forceinline__ f32x4 mfma16(short8 a, short8 b, f32x4 c){
  return __builtin_amdgcn_mfma_f32_16x16x32_bf16(a, b, c, 0, 0, 0);
}
__device__ __forceinline__ f32x16 mfma32(short8 a, short8 b, f32x16 c){
  return __builtin_amdgcn_mfma_f32_32x32x16_bf16(a, b, c, 0, 0, 0);
}
__device__ __forceinline__ void unpk(uint4 u, float* f){
  f[0]=lo2f(u.x); f[1]=hi2f(u.x); f[2]=lo2f(u.y); f[3]=hi2f(u.y);
  f[4]=lo2f(u.z); f[5]=hi2f(u.z); f[6]=lo2f(u.w); f[7]=hi2f(u.w);
}
__device__ __forceinline__ uint4 pk8(const float* f){
  uint4 r;
  r.x = pk2(f[0], f[1]); r.y = pk2(f[2], f[3]);
  r.z = pk2(f[4], f[5]); r.w = pk2(f[6], f[7]);
  return r;
}

// ---------------- weight reorg into MFMA-fragment layouts (f32 -> bf16) ----------------
// Boff16[kc 72][nt 2][lane 64][j 8] : n=nt*16+(lane&15), k=kc*32+((lane>>4)&3)*8+j, tap=k>>8, c=k&255
// Bdcn16[kc 72][nt 8][lane 64][j 8] : o=nt*16+(lane&15), same k decode
// Bup'  [pp 4][kc 32][a4 4][kh 2][n 32][j 8] (32x32 frag, K=512): k=kc*16+kh*8+j, tapd=k>>7, c=k&127
__global__ __launch_bounds__(256) void prep_kernel(const float* __restrict__ w_off,
                                                   const float* __restrict__ w_dcn,
                                                   const float* __restrict__ w_up,
                                                   u16* __restrict__ Boff,
                                                   u16* __restrict__ Bdcn,
                                                   u16* __restrict__ Bup){
  int i = blockIdx.x * 256 + threadIdx.x;
  if (i < 72*2*64*8){
    int j = i & 7, lane = (i >> 3) & 63, nt = (i >> 9) & 1, kc = i >> 10;
    int n = nt*16 + (lane & 15);
    int k = kc*32 + ((lane >> 4) & 3)*8 + j, tap = k >> 8, c = k & 255;
    int ky = tap / 3, kx = tap - ky*3;
    u16 v = 0;
    if (n < 27) v = f2b(w_off[((n*256 + c)*3 + ky)*3 + kx]);
    Boff[i] = v;
  }
  if (i < 72*8*64*8){
    int j = i & 7, lane = (i >> 3) & 63, nt = (i >> 9) & 7, kc = i >> 12;
    int o = nt*16 + (lane & 15);
    int k = kc*32 + ((lane >> 4) & 3)*8 + j, tap = k >> 8, c = k & 255;
    int ky = tap / 3, kx = tap - ky*3;
    Bdcn[i] = f2b(w_dcn[((o*256 + c)*3 + ky)*3 + kx]);
  }
  if (i < 4*32*4*2*32*8){
    int j = i & 7, n = (i >> 3) & 31, kh = (i >> 8) & 1, a4 = (i >> 9) & 3;
    int kc = (i >> 11) & 31, pp = i >> 16;
    int k = kc*16 + kh*8 + j, tapd = k >> 7, c = k & 127;
    int o = a4*32 + n;
    int py = pp >> 1, px = pp & 1, dy = tapd >> 1, dx = tapd & 1;
    Bup[i] = f2b(w_up[((c*128 + o)*4 + (3-(py+2*dy)))*4 + (3-(px+2*dx))]);
  }
}

// ---------------- x NCHW f32 -> NHWC bf16 ----------------
__global__ __launch_bounds__(256) void transpose_kernel(const float* __restrict__ x, u16* __restrict__ xt){
  __shared__ u16 Ls[64][65];
  int blk = blockIdx.x;                 // 1024 = 4b * 64h * 4cb
  int cb = blk & 3, h = (blk >> 2) & 63, b = blk >> 8;
  int t = threadIdx.x;
  int c0 = cb * 64;
  for (int i = 0; i < 16; i++){
    int idx = t + i*256;
    int c = idx >> 6, w = idx & 63;
    Ls[c][w] = f2b(x[((b*256 + c0 + c)*64 + h)*64 + w]);
  }
  __syncthreads();
  for (int i = 0; i < 16; i++){
    int idx = t + i*256;
    int w = idx >> 6, cc = idx & 63;
    xt[(((b*64 + h)*64 + w) << 8) + c0 + cc] = Ls[cc][w];
  }
}

// ---------------- stage 1: offset conv; dbuf 3-phase pipeline, 4-wave K-split ----------------
__global__ __launch_bounds__(256, 8) void convoff_kernel(const u16* __restrict__ xt,
                                                         const u16* __restrict__ Boff,
                                                         const float* __restrict__ b_off,
                                                         float* __restrict__ om){
  __shared__ alignas(16) char smem[16896];    // As dbuf 2x[16px][264]; Ys overlays
  u16* As0 = (u16*)smem;
  u16* As1 = (u16*)(smem + 8448);
  float* Ys = (float*)smem;                   // [4][16][36] = 9216 B (after final barrier)
  int blk = blockIdx.x;                 // 1024 = 4b * 64h * 4wt
  int wt = blk & 3, h = (blk >> 2) & 63, b = blk >> 8;
  int w0 = wt * 16;
  int P0 = (b*64 + h)*64 + w0;
  int t = threadIdx.x;
  int wv = t >> 6, lane = t & 63;
  int ln = lane & 15, q4 = (lane >> 4) & 3;
  int spx = t >> 5, sc16a = t & 31;     // staging: px = spx(+8), c16
  f32x4 acc[2];
  acc[0] = (f32x4){0.f,0.f,0.f,0.f};
  acc[1] = (f32x4){0.f,0.f,0.f,0.f};
  uint4 pf[2];

  // prefetch + stage tap 0
  {
    int ky = -1, kx = -1;
    #pragma unroll
    for (int it = 0; it < 2; it++){
      int px = spx + it*8;
      int y = h + ky, xw = w0 + px + kx;
      pf[it] = make_uint4(0,0,0,0);
      if ((u32)y < 64u && (u32)xw < 64u)
        pf[it] = *(const uint4*)(xt + (((b*64 + y)*64 + xw) << 8) + sc16a*8);
    }
    #pragma unroll
    for (int it = 0; it < 2; it++)
      *(uint4*)(As0 + (spx + it*8)*264 + sc16a*8) = pf[it];
  }
  __syncthreads();

  for (int tap = 0; tap < 9; tap++){
    const u16* cur = (tap & 1) ? As1 : As0;
    u16* nxt = (tap & 1) ? As0 : As1;
    if (tap < 8){
      int tn = tap + 1;
      int ky = tn/3 - 1, kx = tn - (tn/3)*3 - 1;
      #pragma unroll
      for (int it = 0; it < 2; it++){
        int px = spx + it*8;
        int y = h + ky, xw = w0 + px + kx;
        pf[it] = make_uint4(0,0,0,0);
        if ((u32)y < 64u && (u32)xw < 64u)
          pf[it] = *(const uint4*)(xt + (((b*64 + y)*64 + xw) << 8) + sc16a*8);
      }
    }
    #pragma unroll
    for (int q = 0; q < 2; q++){
      int kcl = wv*2 + q;
      int kcg = tap*8 + kcl;
      short8 a = *(const short8*)(cur + ln*264 + kcl*32 + q4*8);
      #pragma unroll
      for (int nt = 0; nt < 2; nt++){
        short8 bb = *(const short8*)(Boff + ((kcg*2 + nt)*64 + lane)*8);
        acc[nt] = mfma16(a, bb, acc[nt]);
      }
    }
    if (tap < 8){
      #pragma unroll
      for (int it = 0; it < 2; it++)
        *(uint4*)(nxt + (spx + it*8)*264 + sc16a*8) = pf[it];
    }
    __syncthreads();
  }
  // K-split reduction (Ys overlays As; loop's final barrier protects)
  #pragma unroll
  for (int nt = 0; nt < 2; nt++)
    #pragma unroll
    for (int r = 0; r < 4; r++)
      Ys[(wv*16 + q4*4 + r)*36 + nt*16 + ln] = acc[nt][r];
  __syncthreads();
  {
    int px = t >> 4, s = t & 15;
    #pragma unroll
    for (int half = 0; half < 2; half++){
      int n = s + half*16;
      if (n < 27){
        float sum = Ys[(px)*36 + n] + Ys[(16 + px)*36 + n]
                  + Ys[(32 + px)*36 + n] + Ys[(48 + px)*36 + n] + b_off[n];
        om[(P0 + px)*32 + n] = sum;
      }
    }
  }
}

// ---------------- stage 2: mdcn; N-split waves, dbuf 3-phase gather pipeline ----------------
__global__ __launch_bounds__(256, 6) void mdcn_kernel(const u16* __restrict__ xt,
                                                      const float* __restrict__ om,
                                                      const u16* __restrict__ Bdcn,
                                                      const float* __restrict__ b_dcn,
                                                      u16* __restrict__ yb){
  __shared__ alignas(16) char smem[18944];    // As dbuf 2x8448 + omL 2048; Lp overlays upper
  u16* As0 = (u16*)smem;
  u16* As1 = (u16*)(smem + 8448);
  float* omL = (float*)(smem + 16896);        // [16][32]
  u16* Lp = (u16*)(smem + 8448);              // [16][136] = 4352 B (overlays As1)
  int blk = blockIdx.x;                 // 1024 = 4b * 64h * 4wt
  int wt = blk & 3, h = (blk >> 2) & 63, b = blk >> 8;
  int w0 = wt * 16;
  int P0 = (b*64 + h)*64 + w0;
  int t = threadIdx.x;
  int wv = t >> 6, lane = t & 63;
  int m = lane & 31, kh = lane >> 5;
  int ln = lane & 15, q4 = (lane >> 4) & 3;
  omL[t]       = om[P0*32 + t];
  omL[256 + t] = om[P0*32 + 256 + t];
  float bias0 = b_dcn[wv*32 + ln];
  float bias1 = b_dcn[wv*32 + 16 + ln];
  __syncthreads();

  f32x4 acc[2];
  acc[0] = (f32x4){0.f,0.f,0.f,0.f};
  acc[1] = (f32x4){0.f,0.f,0.f,0.f};
  uint4 pu0[4], pu1[4];
  float pwt[4], pwb[4];

  auto prefetch = [&](int tap){
    int ky = tap/3, kx = tap - (tap/3)*3;
    #pragma unroll
    for (int e = 0; e < 4; e++){
      int p = wv*4 + e;
      float dy  = omL[p*32 + 2*tap];
      float dxv = omL[p*32 + 2*tap + 1];
      float mk  = 1.f / (1.f + __expf(-omL[p*32 + 18 + tap]));
      float ys = (float)(h - 1 + ky) + dy;
      float xs = (float)(w0 + p - 1 + kx) + dxv;
      float y0f = floorf(ys), x0f = floorf(xs);
      float ly = ys - y0f, lx = xs - x0f;
      int y0 = (int)y0f, x0 = (int)x0f;
      int xx = x0 + kh;
      bool vx = (u32)xx < 64u;
      bool v0 = vx && ((u32)y0 < 64u);
      bool v1 = vx && ((u32)(y0+1) < 64u);
      float cwt = kh ? lx : (1.f - lx);
      pwt[e] = (1.f - ly) * cwt * mk;
      pwb[e] = ly * cwt * mk;
      const u16* base = xt + (((b*64 + y0)*64 + xx) << 8) + m*8;
      uint4 z = make_uint4(0,0,0,0);
      pu0[e] = v0 ? *(const uint4*)(base) : z;
      pu1[e] = v1 ? *(const uint4*)(base + (64 << 8)) : z;
    }
  };
  auto blend_write = [&](u16* dst){
    #pragma unroll
    for (int e = 0; e < 4; e++){
      int p = wv*4 + e;
      float f0[8], f1[8], s[8];
      unpk(pu0[e], f0); unpk(pu1[e], f1);
      #pragma unroll
      for (int j = 0; j < 8; j++) s[j] = pwt[e]*f0[j] + pwb[e]*f1[j];
      #pragma unroll
      for (int j = 0; j < 8; j++) s[j] += __shfl_xor(s[j], 32);
      if (kh == 0)
        *(uint4*)(dst + p*264 + m*8) = pk8(s);
    }
  };

  prefetch(0);
  blend_write(As0);
  __syncthreads();

  for (int tap = 0; tap < 9; tap++){
    const u16* cur = (tap & 1) ? As1 : As0;
    u16* nxt = (tap & 1) ? As0 : As1;
    if (tap < 8) prefetch(tap + 1);
    #pragma unroll
    for (int kc = 0; kc < 8; kc++){
      short8 a = *(const short8*)(cur + ln*264 + kc*32 + q4*8);
      int kcg = tap*8 + kc;
      #pragma unroll
      for (int nt2 = 0; nt2 < 2; nt2++){
        int nt = wv*2 + nt2;
        short8 bb = *(const short8*)(Bdcn + ((kcg*8 + nt)*64 + lane)*8);
        acc[nt2] = mfma16(a, bb, acc[nt2]);
      }
    }
    if (tap < 8) blend_write(nxt);
    __syncthreads();
  }
  // epilogue: pack 16px x 32ch (this wave) via LDS, coalesced NHWC store
  #pragma unroll
  for (int nt2 = 0; nt2 < 2; nt2++){
    int ch = wv*32 + nt2*16 + ln;
    float bias = nt2 ? bias1 : bias0;
    #pragma unroll
    for (int r = 0; r < 4; r++){
      int px = q4*4 + r;
      Lp[px*136 + ch] = (u16)(rne(acc[nt2][r] + bias) >> 16);
    }
  }
  __syncthreads();
  {
    int px = t >> 4, cg = t & 15;
    uint4 u = *(const uint4*)(Lp + px*136 + cg*8);
    *(uint4*)(yb + (P0 + px)*128 + cg*8) = u;
  }
}

// ---------------- BN1 stats: per-channel sum/sumsq over NHWC bf16 ----------------
__global__ __launch_bounds__(256) void bnstats_kernel(const u16* __restrict__ src,
                                                      float* __restrict__ st, int npix){
  __shared__ float red[256];
  int t = threadIdx.x;
  int ch = t & 127, half = t >> 7;
  float s = 0.f, ss = 0.f;
  for (int p = blockIdx.x*2 + half; p < npix; p += gridDim.x*2){
    float v = b2f(src[p*128 + ch]);
    s += v; ss += v*v;
  }
  red[t] = s; __syncthreads();
  if (t < 128) atomicAdd(&st[t], red[t] + red[t+128]);
  __syncthreads();
  red[t] = ss; __syncthreads();
  if (t < 128) atomicAdd(&st[128 + t], red[t] + red[t+128]);
}

// ---------------- BN2 stats: per-channel over NCHW bf16 (no atomics) ----------------
__global__ __launch_bounds__(256) void bnstats_nchw_kernel(const u16* __restrict__ y2n,
                                                           float* __restrict__ st){
  __shared__ float red[8];
  int ch = blockIdx.x;                  // 128
  int t = threadIdx.x;
  int wv = t >> 6, lane = t & 63;
  float s = 0.f, ss = 0.f;
  for (int b = 0; b < 4; b++){
    const u16* base = y2n + (((b*128 + ch) << 14)) + t*8;
    #pragma unroll
    for (int it = 0; it < 8; it++){
      uint4 u = *(const uint4*)(base + it*2048);
      float f[8]; unpk(u, f);
      #pragma unroll
      for (int e = 0; e < 8; e++){ s += f[e]; ss += f[e]*f[e]; }
    }
  }
  #pragma unroll
  for (int o = 32; o >= 1; o >>= 1){
    s  += __shfl_xor(s, o);
    ss += __shfl_xor(ss, o);
  }
  if (lane == 0){ red[wv*2] = s; red[wv*2+1] = ss; }
  __syncthreads();
  if (t == 0) st[ch]       = red[0] + red[2] + red[4] + red[6];
  if (t == 1) st[128 + ch] = red[1] + red[3] + red[5] + red[7];
}

// ---------------- BN finalize ----------------
__global__ __launch_bounds__(128) void bnfin_kernel(const float* __restrict__ stats,
                                                    const float* __restrict__ gamma,
                                                    const float* __restrict__ beta,
                                                    float2* __restrict__ bn,
                                                    float invN){
  int o = threadIdx.x;
  float mean = stats[o] * invN;
  float var  = stats[128 + o] * invN - mean*mean;
  float inv  = rsqrtf(var + 1e-5f);
  float sc   = gamma[o] * inv;
  bn[o] = make_float2(sc, beta[o] - mean * sc);
}

// ---------------- stage 4: deconv; half-row blocks, N-split waves, NCHW bf16 out ----------------
__global__ __launch_bounds__(256, 6) void deconv_kernel(const u16* __restrict__ yb,
                                                        const float2* __restrict__ bn1,
                                                        const u16* __restrict__ Bup,
                                                        u16* __restrict__ y2n){
  __shared__ alignas(16) char smem[19520];    // Ls [2][34][136] u16 (18496) | Lo [64][136] overlay; bnL 1024
  u16* Ls = (u16*)smem;
  u16* Lo = (u16*)smem;
  float2* bnL = (float2*)(smem + 18496);
  int blk = blockIdx.x;                 // 1024 = 4b * 128yy * 2half
  int half = blk & 1, yy = (blk >> 1) & 127, b = blk >> 8;
  int pary = yy & 1;
  int hs = (yy - 2 + pary) >> 1;
  int X0 = half * 64, wbase = half*32 - 1;
  int t = threadIdx.x;
  if (t < 128) bnL[t] = bn1[t];
  __syncthreads();
  // stage 2 rows x 34 cols x 128 ch, bn1+relu fused
  #pragma unroll
  for (int it = 0; it < 5; it++){
    int idx = it*256 + t;
    if (idx < 1088){
      int r = idx / 544, rem = idx - r*544;
      int cc = rem >> 4, c16 = rem & 15;
      int hh = hs + r, w_in = wbase + cc;
      uint4 u = make_uint4(0,0,0,0);
      if ((u32)hh < 64u && (u32)w_in < 64u)
        u = *(const uint4*)(yb + (((b*64 + hh)*64 + w_in) << 7) + c16*8);
      float f[8]; unpk(u, f);
      float o[8];
      #pragma unroll
      for (int e = 0; e < 8; e++){
        float2 sc = bnL[c16*8 + e];
        o[e] = fmaxf(0.f, fmaf(sc.x, f[e], sc.y));
      }
      *(uint4*)(Ls + (r*34 + cc)*136 + c16*8) = pk8(o);
    }
  }
  __syncthreads();

  int wv = t >> 6, lane = t & 63;
  int m = lane & 31, kh = lane >> 5;
  int parx = wv & 1, nh = wv >> 1;
  int pp = pary*2 + parx;
  f32x16 acc[2];
  acc[0] = (f32x16){0.f};
  acc[1] = (f32x16){0.f};

  #pragma unroll
  for (int tapd = 0; tapd < 4; tapd++){
    int dyy = tapd >> 1, dxx = tapd & 1;
    const u16* lp = Ls + ((dyy*34 + m + parx + dxx)*136);
    #pragma unroll
    for (int q = 0; q < 8; q++){
      short8 a = *(const short8*)(lp + q*16 + kh*8);
      #pragma unroll
      for (int nt2 = 0; nt2 < 2; nt2++){
        int a4 = nh*2 + nt2;
        short8 bb = *(const short8*)(Bup + ((((pp*32 + tapd*8 + q)*4 + a4)*2 + kh)*32 + m)*8);
        acc[nt2] = mfma32(a, bb, acc[nt2]);
      }
    }
  }
  __syncthreads();                      // done reading Ls; Lo overlays
  #pragma unroll
  for (int nt2 = 0; nt2 < 2; nt2++){
    int ch = (nh*2 + nt2)*32 + m;
    #pragma unroll
    for (int r = 0; r < 16; r++){
      int mrow = (r & 3) + 8*(r >> 2) + 4*kh;
      int xl = parx + 2*mrow;
      Lo[xl*136 + ch] = (u16)(rne(acc[nt2][r]) >> 16);
    }
  }
  __syncthreads();
  // readout: NCHW bf16, 64B contiguous per thread
  {
    int ch = t >> 1, xh = t & 1;
    u16* gp = y2n + ((b*128 + ch)*128 + yy)*128 + X0 + xh*32;
    #pragma unroll
    for (int g = 0; g < 4; g++){
      u32 r4[4];
      #pragma unroll
      for (int e = 0; e < 4; e++){
        u32 lo = Lo[(xh*32 + g*8 + 2*e)*136 + ch];
        u32 hi = Lo[(xh*32 + g*8 + 2*e + 1)*136 + ch];
        r4[e] = lo | (hi << 16);
      }
      *(uint4*)(gp + g*8) = make_uint4(r4[0], r4[1], r4[2], r4[3]);
    }
  }
}

// ---------------- stage 5: BN2 + ReLU elementwise NCHW, f32 out ----------------
__global__ __launch_bounds__(256) void final_kernel(const u16* __restrict__ y2n,
                                                    const float2* __restrict__ bn2,
                                                    float* __restrict__ outp){
  int gid = blockIdx.x*256 + threadIdx.x;   // 4096 blocks
  int idx = gid * 8;
  int ch = (idx >> 14) & 127;
  float2 sc = bn2[ch];
  uint4 u = *(const uint4*)(y2n + idx);
  float f[8]; unpk(u, f);
  float4 o0, o1;
  o0.x = fmaxf(0.f, fmaf(sc.x, f[0], sc.y));
  o0.y = fmaxf(0.f, fmaf(sc.x, f[1], sc.y));
  o0.z = fmaxf(0.f, fmaf(sc.x, f[2], sc.y));
  o0.w = fmaxf(0.f, fmaf(sc.x, f[3], sc.y));
  o1.x = fmaxf(0.f, fmaf(sc.x, f[4], sc.y));
  o1.y = fmaxf(0.f, fmaf(sc.x, f[5], sc.y));
  o1.z = fmaxf(0.f, fmaf(sc.x, f[6], sc.y));
  o1.w = fmaxf(0.f, fmaf(sc.x, f[7], sc.y));
  *(float4*)(outp + idx)     = o0;
  *(float4*)(outp + idx + 4) = o1;
}

extern "C" void kernel_launch(void* const* d_in, const int* in_sizes, int n_in,
                              void* d_out, int out_size, void* d_ws, size_t ws_size,
                              hipStream_t stream) {
  const float* x      = (const float*)d_in[0];
  const float* w_off  = (const float*)d_in[1];
  const float* b_off  = (const float*)d_in[2];
  const float* w_dcn  = (const float*)d_in[3];
  const float* b_dcn  = (const float*)d_in[4];
  const float* gamma1 = (const float*)d_in[5];
  const float* beta1  = (const float*)d_in[6];
  const float* w_up   = (const float*)d_in[7];
  const float* gamma2 = (const float*)d_in[8];
  const float* beta2  = (const float*)d_in[9];

  char* ws = (char*)d_ws;
  u16*   xt    = (u16*)(ws + OFF_XT);
  float* om    = (float*)(ws + OFF_OM);
  u16*   yb    = (u16*)(ws + OFF_Y);
  u16*   y2n   = (u16*)(ws + OFF_Y2);
  u16*   Boff  = (u16*)(ws + OFF_BOFF);
  u16*   Bdcn  = (u16*)(ws + OFF_BDCN);
  u16*   Bup   = (u16*)(ws + OFF_BUP);
  float* stats = (float*)(ws + OFF_STATS);
  float2* bn1  = (float2*)(ws + OFF_BN1);
  float2* bn2  = (float2*)(ws + OFF_BN2);

  (void)hipMemsetAsync(stats, 0, 2048, stream);
  prep_kernel<<<1152, 256, 0, stream>>>(w_off, w_dcn, w_up, Boff, Bdcn, Bup);
  transpose_kernel<<<1024, 256, 0, stream>>>(x, xt);
  convoff_kernel<<<1024, 256, 0, stream>>>(xt, Boff, b_off, om);
  mdcn_kernel<<<1024, 256, 0, stream>>>(xt, om, Bdcn, b_dcn, yb);
  bnstats_kernel<<<256, 256, 0, stream>>>(yb, stats, 16384);
  bnfin_kernel<<<1, 128, 0, stream>>>(stats, gamma1, beta1, bn1, 1.f/16384.f);
  deconv_kernel<<<1024, 256, 0, stream>>>(yb, bn1, Bup, y2n);
  bnstats_nchw_kernel<<<128, 256, 0, stream>>>(y2n, stats + 256);
  bnfin_kernel<<<1, 128, 0, stream>>>(stats + 256, gamma2, beta2, bn2, 1.f/65536.f);
  final_kernel<<<4096, 256, 0, stream>>>(y2n, bn2, (float*)d_out);
}

// Round 10
// 249.188 us; speedup vs baseline: 1.2396x; 1.2396x over previous
//
#include <hip/hip_runtime.h>
#include <hip/hip_bf16.h>

typedef __attribute__((ext_vector_type(8))) short short8;
typedef __attribute__((ext_vector_type(4))) float f32x4;
typedef __attribute__((ext_vector_type(16))) float f32x16;
typedef unsigned short u16;
typedef unsigned int u32;

// ---------------- workspace layout (bytes) ----------------
#define OFF_XT      0u          // x NHWC bf16: 4*64*64*256 = 8388608 B
#define OFF_OM      8388608u    // offsets fp32: 16384*32*4  = 2097152 B
#define OFF_Y       10485760u   // mdcn out NHWC bf16: 16384*128*2 = 4194304 B
#define OFF_Y2      14680064u   // deconv out NCHW bf16: 4*128*128*128*2 = 16777216 B
#define OFF_BOFF    31457280u   // Boff16 [72][2][64][8] bf16 = 147456 B
#define OFF_BDCN    31604736u   // Bdcn16 [72][8][64][8] bf16 = 589824 B
#define OFF_BUP     32194560u   // Bup'  [4][32][4][2][32][8] bf16 = 524288 B
#define OFF_STATS   32718848u   // stats1 sum/ss [256] + stats2 [256] f32 = 2048 B
#define OFF_BN1     32720896u   // float2[128]
#define OFF_BN2     32721920u   // float2[128]

__device__ __forceinline__ float lo2f(u32 u){ u32 v = u << 16; float f; __builtin_memcpy(&f, &v, 4); return f; }
__device__ __forceinline__ float hi2f(u32 u){ u32 v = u & 0xffff0000u; float f; __builtin_memcpy(&f, &v, 4); return f; }
__device__ __forceinline__ float b2f(u16 v){ u32 u = ((u32)v) << 16; float f; __builtin_memcpy(&f, &u, 4); return f; }
__device__ __forceinline__ u16 f2b(float f){ __hip_bfloat16 h = __float2bfloat16(f); u16 r; __builtin_memcpy(&r, &h, 2); return r; }
// fast RNE f32->bf16 (finite values only)
__device__ __forceinline__ u32 rne(float f){ u32 u; __builtin_memcpy(&u, &f, 4); return u + 0x7FFFu + ((u >> 16) & 1u); }
__device__ __forceinline__ u32 pk2(float f0, float f1){ return (rne(f0) >> 16) | (rne(f1) & 0xFFFF0000u); }

__device__ __forceinline__ f32x4 mfma16(short8 a, short8 b, f32x4 c){
  return __builtin_amdgcn_mfma_f32_16x16x32_bf16(a, b, c, 0, 0, 0);
}
__device__ __forceinline__ f32x16 mfma32(short8 a, short8 b, f32x16 c){
  return __builtin_amdgcn_mfma_f32_32x32x16_bf16(a, b, c, 0, 0, 0);
}
__device__ __forceinline__ void unpk(uint4 u, float* f){
  f[0]=lo2f(u.x); f[1]=hi2f(u.x); f[2]=lo2f(u.y); f[3]=hi2f(u.y);
  f[4]=lo2f(u.z); f[5]=hi2f(u.z); f[6]=lo2f(u.w); f[7]=hi2f(u.w);
}
__device__ __forceinline__ uint4 pk8(const float* f){
  uint4 r;
  r.x = pk2(f[0], f[1]); r.y = pk2(f[2], f[3]);
  r.z = pk2(f[4], f[5]); r.w = pk2(f[6], f[7]);
  return r;
}

// ---------------- weight reorg into MFMA-fragment layouts (f32 -> bf16) ----------------
// Boff16[kc 72][nt 2][lane 64][j 8] : n=nt*16+(lane&15), k=kc*32+((lane>>4)&3)*8+j, tap=k>>8, c=k&255
// Bdcn16[kc 72][nt 8][lane 64][j 8] : o=nt*16+(lane&15), same k decode
// Bup'  [pp 4][kc 32][a4 4][kh 2][n 32][j 8] (32x32 frag, K=512): k=kc*16+kh*8+j, tapd=k>>7, c=k&127
__global__ __launch_bounds__(256) void prep_kernel(const float* __restrict__ w_off,
                                                   const float* __restrict__ w_dcn,
                                                   const float* __restrict__ w_up,
                                                   u16* __restrict__ Boff,
                                                   u16* __restrict__ Bdcn,
                                                   u16* __restrict__ Bup){
  int i = blockIdx.x * 256 + threadIdx.x;
  if (i < 72*2*64*8){
    int j = i & 7, lane = (i >> 3) & 63, nt = (i >> 9) & 1, kc = i >> 10;
    int n = nt*16 + (lane & 15);
    int k = kc*32 + ((lane >> 4) & 3)*8 + j, tap = k >> 8, c = k & 255;
    int ky = tap / 3, kx = tap - ky*3;
    u16 v = 0;
    if (n < 27) v = f2b(w_off[((n*256 + c)*3 + ky)*3 + kx]);
    Boff[i] = v;
  }
  if (i < 72*8*64*8){
    int j = i & 7, lane = (i >> 3) & 63, nt = (i >> 9) & 7, kc = i >> 12;
    int o = nt*16 + (lane & 15);
    int k = kc*32 + ((lane >> 4) & 3)*8 + j, tap = k >> 8, c = k & 255;
    int ky = tap / 3, kx = tap - ky*3;
    Bdcn[i] = f2b(w_dcn[((o*256 + c)*3 + ky)*3 + kx]);
  }
  if (i < 4*32*4*2*32*8){
    int j = i & 7, n = (i >> 3) & 31, kh = (i >> 8) & 1, a4 = (i >> 9) & 3;
    int kc = (i >> 11) & 31, pp = i >> 16;
    int k = kc*16 + kh*8 + j, tapd = k >> 7, c = k & 127;
    int o = a4*32 + n;
    int py = pp >> 1, px = pp & 1, dy = tapd >> 1, dx = tapd & 1;
    Bup[i] = f2b(w_up[((c*128 + o)*4 + (3-(py+2*dy)))*4 + (3-(px+2*dx))]);
  }
}

// ---------------- x NCHW f32 -> NHWC bf16 ----------------
__global__ __launch_bounds__(256) void transpose_kernel(const float* __restrict__ x, u16* __restrict__ xt){
  __shared__ u16 Ls[64][65];
  int blk = blockIdx.x;                 // 1024 = 4b * 64h * 4cb
  int cb = blk & 3, h = (blk >> 2) & 63, b = blk >> 8;
  int t = threadIdx.x;
  int c0 = cb * 64;
  for (int i = 0; i < 16; i++){
    int idx = t + i*256;
    int c = idx >> 6, w = idx & 63;
    Ls[c][w] = f2b(x[((b*256 + c0 + c)*64 + h)*64 + w]);
  }
  __syncthreads();
  for (int i = 0; i < 16; i++){
    int idx = t + i*256;
    int w = idx >> 6, cc = idx & 63;
    xt[(((b*64 + h)*64 + w) << 8) + c0 + cc] = Ls[cc][w];
  }
}

// ---------------- stage 1: offset conv; dbuf 3-phase pipeline, 4-wave K-split ----------------
__global__ __launch_bounds__(256, 8) void convoff_kernel(const u16* __restrict__ xt,
                                                         const u16* __restrict__ Boff,
                                                         const float* __restrict__ b_off,
                                                         float* __restrict__ om){
  __shared__ alignas(16) char smem[16896];    // As dbuf 2x[16px][264]; Ys overlays
  u16* As0 = (u16*)smem;
  u16* As1 = (u16*)(smem + 8448);
  float* Ys = (float*)smem;                   // [4][16][36] = 9216 B (after final barrier)
  int blk = blockIdx.x;                 // 1024 = 4b * 64h * 4wt
  int wt = blk & 3, h = (blk >> 2) & 63, b = blk >> 8;
  int w0 = wt * 16;
  int P0 = (b*64 + h)*64 + w0;
  int t = threadIdx.x;
  int wv = t >> 6, lane = t & 63;
  int ln = lane & 15, q4 = (lane >> 4) & 3;
  int spx = t >> 5, sc16a = t & 31;     // staging: px = spx(+8), c16
  f32x4 acc[2];
  acc[0] = (f32x4){0.f,0.f,0.f,0.f};
  acc[1] = (f32x4){0.f,0.f,0.f,0.f};
  uint4 pf[2];

  // prefetch + stage tap 0
  {
    int ky = -1, kx = -1;
    #pragma unroll
    for (int it = 0; it < 2; it++){
      int px = spx + it*8;
      int y = h + ky, xw = w0 + px + kx;
      pf[it] = make_uint4(0,0,0,0);
      if ((u32)y < 64u && (u32)xw < 64u)
        pf[it] = *(const uint4*)(xt + (((b*64 + y)*64 + xw) << 8) + sc16a*8);
    }
    #pragma unroll
    for (int it = 0; it < 2; it++)
      *(uint4*)(As0 + (spx + it*8)*264 + sc16a*8) = pf[it];
  }
  __syncthreads();

  for (int tap = 0; tap < 9; tap++){
    const u16* cur = (tap & 1) ? As1 : As0;
    u16* nxt = (tap & 1) ? As0 : As1;
    if (tap < 8){
      int tn = tap + 1;
      int ky = tn/3 - 1, kx = tn - (tn/3)*3 - 1;
      #pragma unroll
      for (int it = 0; it < 2; it++){
        int px = spx + it*8;
        int y = h + ky, xw = w0 + px + kx;
        pf[it] = make_uint4(0,0,0,0);
        if ((u32)y < 64u && (u32)xw < 64u)
          pf[it] = *(const uint4*)(xt + (((b*64 + y)*64 + xw) << 8) + sc16a*8);
      }
    }
    #pragma unroll
    for (int q = 0; q < 2; q++){
      int kcl = wv*2 + q;
      int kcg = tap*8 + kcl;
      short8 a = *(const short8*)(cur + ln*264 + kcl*32 + q4*8);
      #pragma unroll
      for (int nt = 0; nt < 2; nt++){
        short8 bb = *(const short8*)(Boff + ((kcg*2 + nt)*64 + lane)*8);
        acc[nt] = mfma16(a, bb, acc[nt]);
      }
    }
    if (tap < 8){
      #pragma unroll
      for (int it = 0; it < 2; it++)
        *(uint4*)(nxt + (spx + it*8)*264 + sc16a*8) = pf[it];
    }
    __syncthreads();
  }
  // K-split reduction (Ys overlays As; loop's final barrier protects)
  #pragma unroll
  for (int nt = 0; nt < 2; nt++)
    #pragma unroll
    for (int r = 0; r < 4; r++)
      Ys[(wv*16 + q4*4 + r)*36 + nt*16 + ln] = acc[nt][r];
  __syncthreads();
  {
    int px = t >> 4, s = t & 15;
    #pragma unroll
    for (int half = 0; half < 2; half++){
      int n = s + half*16;
      if (n < 27){
        float sum = Ys[(px)*36 + n] + Ys[(16 + px)*36 + n]
                  + Ys[(32 + px)*36 + n] + Ys[(48 + px)*36 + n] + b_off[n];
        om[(P0 + px)*32 + n] = sum;
      }
    }
  }
}

// ---------------- stage 2: mdcn; N-split waves, dbuf 3-phase gather pipeline ----------------
// __launch_bounds__(256,4): 128-VGPR cap — holds the 8-uint4 prefetch window
// without spilling (R9's (256,6) capped at 40 VGPRs -> scratch spill ->
// FETCH_SIZE 195 MB). 4 blocks/CU via LDS 18.9 KB anyway.
__global__ __launch_bounds__(256, 4) void mdcn_kernel(const u16* __restrict__ xt,
                                                      const float* __restrict__ om,
                                                      const u16* __restrict__ Bdcn,
                                                      const float* __restrict__ b_dcn,
                                                      u16* __restrict__ yb){
  __shared__ alignas(16) char smem[18944];    // As dbuf 2x8448 + omL 2048; Lp overlays upper
  u16* As0 = (u16*)smem;
  u16* As1 = (u16*)(smem + 8448);
  float* omL = (float*)(smem + 16896);        // [16][32]
  u16* Lp = (u16*)(smem + 8448);              // [16][136] = 4352 B (overlays As1)
  int blk = blockIdx.x;                 // 1024 = 4b * 64h * 4wt
  int wt = blk & 3, h = (blk >> 2) & 63, b = blk >> 8;
  int w0 = wt * 16;
  int P0 = (b*64 + h)*64 + w0;
  int t = threadIdx.x;
  int wv = t >> 6, lane = t & 63;
  int m = lane & 31, kh = lane >> 5;
  int ln = lane & 15, q4 = (lane >> 4) & 3;
  omL[t]       = om[P0*32 + t];
  omL[256 + t] = om[P0*32 + 256 + t];
  float bias0 = b_dcn[wv*32 + ln];
  float bias1 = b_dcn[wv*32 + 16 + ln];
  __syncthreads();

  f32x4 acc[2];
  acc[0] = (f32x4){0.f,0.f,0.f,0.f};
  acc[1] = (f32x4){0.f,0.f,0.f,0.f};
  uint4 pu0[4], pu1[4];
  float pwt[4], pwb[4];

  auto prefetch = [&](int tap){
    int ky = tap/3, kx = tap - (tap/3)*3;
    #pragma unroll
    for (int e = 0; e < 4; e++){
      int p = wv*4 + e;
      float dy  = omL[p*32 + 2*tap];
      float dxv = omL[p*32 + 2*tap + 1];
      float mk  = 1.f / (1.f + __expf(-omL[p*32 + 18 + tap]));
      float ys = (float)(h - 1 + ky) + dy;
      float xs = (float)(w0 + p - 1 + kx) + dxv;
      float y0f = floorf(ys), x0f = floorf(xs);
      float ly = ys - y0f, lx = xs - x0f;
      int y0 = (int)y0f, x0 = (int)x0f;
      int xx = x0 + kh;
      bool vx = (u32)xx < 64u;
      bool v0 = vx && ((u32)y0 < 64u);
      bool v1 = vx && ((u32)(y0+1) < 64u);
      float cwt = kh ? lx : (1.f - lx);
      pwt[e] = (1.f - ly) * cwt * mk;
      pwb[e] = ly * cwt * mk;
      const u16* base = xt + (((b*64 + y0)*64 + xx) << 8) + m*8;
      uint4 z = make_uint4(0,0,0,0);
      pu0[e] = v0 ? *(const uint4*)(base) : z;
      pu1[e] = v1 ? *(const uint4*)(base + (64 << 8)) : z;
    }
  };
  auto blend_write = [&](u16* dst){
    #pragma unroll
    for (int e = 0; e < 4; e++){
      int p = wv*4 + e;
      float f0[8], f1[8], s[8];
      unpk(pu0[e], f0); unpk(pu1[e], f1);
      #pragma unroll
      for (int j = 0; j < 8; j++) s[j] = pwt[e]*f0[j] + pwb[e]*f1[j];
      #pragma unroll
      for (int j = 0; j < 8; j++) s[j] += __shfl_xor(s[j], 32);
      if (kh == 0)
        *(uint4*)(dst + p*264 + m*8) = pk8(s);
    }
  };

  prefetch(0);
  blend_write(As0);
  __syncthreads();

  for (int tap = 0; tap < 9; tap++){
    const u16* cur = (tap & 1) ? As1 : As0;
    u16* nxt = (tap & 1) ? As0 : As1;
    if (tap < 8) prefetch(tap + 1);
    #pragma unroll
    for (int kc = 0; kc < 8; kc++){
      short8 a = *(const short8*)(cur + ln*264 + kc*32 + q4*8);
      int kcg = tap*8 + kc;
      #pragma unroll
      for (int nt2 = 0; nt2 < 2; nt2++){
        int nt = wv*2 + nt2;
        short8 bb = *(const short8*)(Bdcn + ((kcg*8 + nt)*64 + lane)*8);
        acc[nt2] = mfma16(a, bb, acc[nt2]);
      }
    }
    if (tap < 8) blend_write(nxt);
    __syncthreads();
  }
  // epilogue: pack 16px x 32ch (this wave) via LDS, coalesced NHWC store
  #pragma unroll
  for (int nt2 = 0; nt2 < 2; nt2++){
    int ch = wv*32 + nt2*16 + ln;
    float bias = nt2 ? bias1 : bias0;
    #pragma unroll
    for (int r = 0; r < 4; r++){
      int px = q4*4 + r;
      Lp[px*136 + ch] = (u16)(rne(acc[nt2][r] + bias) >> 16);
    }
  }
  __syncthreads();
  {
    int px = t >> 4, cg = t & 15;
    uint4 u = *(const uint4*)(Lp + px*136 + cg*8);
    *(uint4*)(yb + (P0 + px)*128 + cg*8) = u;
  }
}

// ---------------- BN1 stats: per-channel sum/sumsq over NHWC bf16 ----------------
__global__ __launch_bounds__(256) void bnstats_kernel(const u16* __restrict__ src,
                                                      float* __restrict__ st, int npix){
  __shared__ float red[256];
  int t = threadIdx.x;
  int ch = t & 127, half = t >> 7;
  float s = 0.f, ss = 0.f;
  for (int p = blockIdx.x*2 + half; p < npix; p += gridDim.x*2){
    float v = b2f(src[p*128 + ch]);
    s += v; ss += v*v;
  }
  red[t] = s; __syncthreads();
  if (t < 128) atomicAdd(&st[t], red[t] + red[t+128]);
  __syncthreads();
  red[t] = ss; __syncthreads();
  if (t < 128) atomicAdd(&st[128 + t], red[t] + red[t+128]);
}

// ---------------- BN2 stats: per-channel over NCHW bf16 (no atomics) ----------------
__global__ __launch_bounds__(256) void bnstats_nchw_kernel(const u16* __restrict__ y2n,
                                                           float* __restrict__ st){
  __shared__ float red[8];
  int ch = blockIdx.x;                  // 128
  int t = threadIdx.x;
  int wv = t >> 6, lane = t & 63;
  float s = 0.f, ss = 0.f;
  for (int b = 0; b < 4; b++){
    const u16* base = y2n + (((b*128 + ch) << 14)) + t*8;
    #pragma unroll
    for (int it = 0; it < 8; it++){
      uint4 u = *(const uint4*)(base + it*2048);
      float f[8]; unpk(u, f);
      #pragma unroll
      for (int e = 0; e < 8; e++){ s += f[e]; ss += f[e]*f[e]; }
    }
  }
  #pragma unroll
  for (int o = 32; o >= 1; o >>= 1){
    s  += __shfl_xor(s, o);
    ss += __shfl_xor(ss, o);
  }
  if (lane == 0){ red[wv*2] = s; red[wv*2+1] = ss; }
  __syncthreads();
  if (t == 0) st[ch]       = red[0] + red[2] + red[4] + red[6];
  if (t == 1) st[128 + ch] = red[1] + red[3] + red[5] + red[7];
}

// ---------------- BN finalize ----------------
__global__ __launch_bounds__(128) void bnfin_kernel(const float* __restrict__ stats,
                                                    const float* __restrict__ gamma,
                                                    const float* __restrict__ beta,
                                                    float2* __restrict__ bn,
                                                    float invN){
  int o = threadIdx.x;
  float mean = stats[o] * invN;
  float var  = stats[128 + o] * invN - mean*mean;
  float inv  = rsqrtf(var + 1e-5f);
  float sc   = gamma[o] * inv;
  bn[o] = make_float2(sc, beta[o] - mean * sc);
}

// ---------------- stage 4: deconv; half-row blocks, N-split waves, NCHW bf16 out ----------------
__global__ __launch_bounds__(256, 6) void deconv_kernel(const u16* __restrict__ yb,
                                                        const float2* __restrict__ bn1,
                                                        const u16* __restrict__ Bup,
                                                        u16* __restrict__ y2n){
  __shared__ alignas(16) char smem[19520];    // Ls [2][34][136] u16 (18496) | Lo [64][136] overlay; bnL 1024
  u16* Ls = (u16*)smem;
  u16* Lo = (u16*)smem;
  float2* bnL = (float2*)(smem + 18496);
  int blk = blockIdx.x;                 // 1024 = 4b * 128yy * 2half
  int half = blk & 1, yy = (blk >> 1) & 127, b = blk >> 8;
  int pary = yy & 1;
  int hs = (yy - 2 + pary) >> 1;
  int X0 = half * 64, wbase = half*32 - 1;
  int t = threadIdx.x;
  if (t < 128) bnL[t] = bn1[t];
  __syncthreads();
  // stage 2 rows x 34 cols x 128 ch, bn1+relu fused
  #pragma unroll
  for (int it = 0; it < 5; it++){
    int idx = it*256 + t;
    if (idx < 1088){
      int r = idx / 544, rem = idx - r*544;
      int cc = rem >> 4, c16 = rem & 15;
      int hh = hs + r, w_in = wbase + cc;
      uint4 u = make_uint4(0,0,0,0);
      if ((u32)hh < 64u && (u32)w_in < 64u)
        u = *(const uint4*)(yb + (((b*64 + hh)*64 + w_in) << 7) + c16*8);
      float f[8]; unpk(u, f);
      float o[8];
      #pragma unroll
      for (int e = 0; e < 8; e++){
        float2 sc = bnL[c16*8 + e];
        o[e] = fmaxf(0.f, fmaf(sc.x, f[e], sc.y));
      }
      *(uint4*)(Ls + (r*34 + cc)*136 + c16*8) = pk8(o);
    }
  }
  __syncthreads();

  int wv = t >> 6, lane = t & 63;
  int m = lane & 31, kh = lane >> 5;
  int parx = wv & 1, nh = wv >> 1;
  int pp = pary*2 + parx;
  f32x16 acc[2];
  acc[0] = (f32x16){0.f};
  acc[1] = (f32x16){0.f};

  #pragma unroll
  for (int tapd = 0; tapd < 4; tapd++){
    int dyy = tapd >> 1, dxx = tapd & 1;
    const u16* lp = Ls + ((dyy*34 + m + parx + dxx)*136);
    #pragma unroll
    for (int q = 0; q < 8; q++){
      short8 a = *(const short8*)(lp + q*16 + kh*8);
      #pragma unroll
      for (int nt2 = 0; nt2 < 2; nt2++){
        int a4 = nh*2 + nt2;
        short8 bb = *(const short8*)(Bup + ((((pp*32 + tapd*8 + q)*4 + a4)*2 + kh)*32 + m)*8);
        acc[nt2] = mfma32(a, bb, acc[nt2]);
      }
    }
  }
  __syncthreads();                      // done reading Ls; Lo overlays
  #pragma unroll
  for (int nt2 = 0; nt2 < 2; nt2++){
    int ch = (nh*2 + nt2)*32 + m;
    #pragma unroll
    for (int r = 0; r < 16; r++){
      int mrow = (r & 3) + 8*(r >> 2) + 4*kh;
      int xl = parx + 2*mrow;
      Lo[xl*136 + ch] = (u16)(rne(acc[nt2][r]) >> 16);
    }
  }
  __syncthreads();
  // readout: NCHW bf16, 64B contiguous per thread
  {
    int ch = t >> 1, xh = t & 1;
    u16* gp = y2n + ((b*128 + ch)*128 + yy)*128 + X0 + xh*32;
    #pragma unroll
    for (int g = 0; g < 4; g++){
      u32 r4[4];
      #pragma unroll
      for (int e = 0; e < 4; e++){
        u32 lo = Lo[(xh*32 + g*8 + 2*e)*136 + ch];
        u32 hi = Lo[(xh*32 + g*8 + 2*e + 1)*136 + ch];
        r4[e] = lo | (hi << 16);
      }
      *(uint4*)(gp + g*8) = make_uint4(r4[0], r4[1], r4[2], r4[3]);
    }
  }
}

// ---------------- stage 5: BN2 + ReLU elementwise NCHW, f32 out ----------------
__global__ __launch_bounds__(256) void final_kernel(const u16* __restrict__ y2n,
                                                    const float2* __restrict__ bn2,
                                                    float* __restrict__ outp){
  int gid = blockIdx.x*256 + threadIdx.x;   // 4096 blocks
  int idx = gid * 8;
  int ch = (idx >> 14) & 127;
  float2 sc = bn2[ch];
  uint4 u = *(const uint4*)(y2n + idx);
  float f[8]; unpk(u, f);
  float4 o0, o1;
  o0.x = fmaxf(0.f, fmaf(sc.x, f[0], sc.y));
  o0.y = fmaxf(0.f, fmaf(sc.x, f[1], sc.y));
  o0.z = fmaxf(0.f, fmaf(sc.x, f[2], sc.y));
  o0.w = fmaxf(0.f, fmaf(sc.x, f[3], sc.y));
  o1.x = fmaxf(0.f, fmaf(sc.x, f[4], sc.y));
  o1.y = fmaxf(0.f, fmaf(sc.x, f[5], sc.y));
  o1.z = fmaxf(0.f, fmaf(sc.x, f[6], sc.y));
  o1.w = fmaxf(0.f, fmaf(sc.x, f[7], sc.y));
  *(float4*)(outp + idx)     = o0;
  *(float4*)(outp + idx + 4) = o1;
}

extern "C" void kernel_launch(void* const* d_in, const int* in_sizes, int n_in,
                              void* d_out, int out_size, void* d_ws, size_t ws_size,
                              hipStream_t stream) {
  const float* x      = (const float*)d_in[0];
  const float* w_off  = (const float*)d_in[1];
  const float* b_off  = (const float*)d_in[2];
  const float* w_dcn  = (const float*)d_in[3];
  const float* b_dcn  = (const float*)d_in[4];
  const float* gamma1 = (const float*)d_in[5];
  const float* beta1  = (const float*)d_in[6];
  const float* w_up   = (const float*)d_in[7];
  const float* gamma2 = (const float*)d_in[8];
  const float* beta2  = (const float*)d_in[9];

  char* ws = (char*)d_ws;
  u16*   xt    = (u16*)(ws + OFF_XT);
  float* om    = (float*)(ws + OFF_OM);
  u16*   yb    = (u16*)(ws + OFF_Y);
  u16*   y2n   = (u16*)(ws + OFF_Y2);
  u16*   Boff  = (u16*)(ws + OFF_BOFF);
  u16*   Bdcn  = (u16*)(ws + OFF_BDCN);
  u16*   Bup   = (u16*)(ws + OFF_BUP);
  float* stats = (float*)(ws + OFF_STATS);
  float2* bn1  = (float2*)(ws + OFF_BN1);
  float2* bn2  = (float2*)(ws + OFF_BN2);

  (void)hipMemsetAsync(stats, 0, 2048, stream);
  prep_kernel<<<1152, 256, 0, stream>>>(w_off, w_dcn, w_up, Boff, Bdcn, Bup);
  transpose_kernel<<<1024, 256, 0, stream>>>(x, xt);
  convoff_kernel<<<1024, 256, 0, stream>>>(xt, Boff, b_off, om);
  mdcn_kernel<<<1024, 256, 0, stream>>>(xt, om, Bdcn, b_dcn, yb);
  bnstats_kernel<<<256, 256, 0, stream>>>(yb, stats, 16384);
  bnfin_kernel<<<1, 128, 0, stream>>>(stats, gamma1, beta1, bn1, 1.f/16384.f);
  deconv_kernel<<<1024, 256, 0, stream>>>(yb, bn1, Bup, y2n);
  bnstats_nchw_kernel<<<128, 256, 0, stream>>>(y2n, stats + 256);
  bnfin_kernel<<<1, 128, 0, stream>>>(stats + 256, gamma2, beta2, bn2, 1.f/65536.f);
  final_kernel<<<4096, 256, 0, stream>>>(y2n, bn2, (float*)d_out);
}

// Round 11
// 194.303 us; speedup vs baseline: 1.5897x; 1.2825x over previous
//
#include <hip/hip_runtime.h>
#include <hip/hip_bf16.h>

typedef __attribute__((ext_vector_type(8))) short short8;
typedef __attribute__((ext_vector_type(4))) float f32x4;
typedef __attribute__((ext_vector_type(16))) float f32x16;
typedef unsigned short u16;
typedef unsigned int u32;

// ---------------- workspace layout (bytes) ----------------
#define OFF_XT      0u          // x NHWC bf16: 4*64*64*256 = 8388608 B
#define OFF_OM      8388608u    // offsets fp32: 16384*32*4  = 2097152 B
#define OFF_Y       10485760u   // mdcn out NHWC bf16: 16384*128*2 = 4194304 B
#define OFF_Y2      14680064u   // deconv out NCHW bf16: 4*128*128*128*2 = 16777216 B
#define OFF_BOFF    31457280u   // Boff16 [72][2][64][8] bf16 = 147456 B
#define OFF_BDCN    31604736u   // Bdcn16 [72][8][64][8] bf16 = 589824 B
#define OFF_BUP     32194560u   // Bup'  [4][32][4][2][32][8] bf16 = 524288 B
#define OFF_STATS   32718848u   // stats1 sum/ss [256] + stats2 [256] f32 = 2048 B

__device__ __forceinline__ float lo2f(u32 u){ u32 v = u << 16; float f; __builtin_memcpy(&f, &v, 4); return f; }
__device__ __forceinline__ float hi2f(u32 u){ u32 v = u & 0xffff0000u; float f; __builtin_memcpy(&f, &v, 4); return f; }
__device__ __forceinline__ float b2f(u16 v){ u32 u = ((u32)v) << 16; float f; __builtin_memcpy(&f, &u, 4); return f; }
__device__ __forceinline__ u16 f2b(float f){ __hip_bfloat16 h = __float2bfloat16(f); u16 r; __builtin_memcpy(&r, &h, 2); return r; }
// fast RNE f32->bf16 (finite values only)
__device__ __forceinline__ u32 rne(float f){ u32 u; __builtin_memcpy(&u, &f, 4); return u + 0x7FFFu + ((u >> 16) & 1u); }
__device__ __forceinline__ u32 pk2(float f0, float f1){ return (rne(f0) >> 16) | (rne(f1) & 0xFFFF0000u); }

__device__ __forceinline__ f32x4 mfma16(short8 a, short8 b, f32x4 c){
  return __builtin_amdgcn_mfma_f32_16x16x32_bf16(a, b, c, 0, 0, 0);
}
__device__ __forceinline__ f32x16 mfma32(short8 a, short8 b, f32x16 c){
  return __builtin_amdgcn_mfma_f32_32x32x16_bf16(a, b, c, 0, 0, 0);
}
__device__ __forceinline__ void unpk(uint4 u, float* f){
  f[0]=lo2f(u.x); f[1]=hi2f(u.x); f[2]=lo2f(u.y); f[3]=hi2f(u.y);
  f[4]=lo2f(u.z); f[5]=hi2f(u.z); f[6]=lo2f(u.w); f[7]=hi2f(u.w);
}
__device__ __forceinline__ uint4 pk8(const float* f){
  uint4 r;
  r.x = pk2(f[0], f[1]); r.y = pk2(f[2], f[3]);
  r.z = pk2(f[4], f[5]); r.w = pk2(f[6], f[7]);
  return r;
}

// ---------------- weight reorg into MFMA-fragment layouts (f32 -> bf16) ----------------
__global__ __launch_bounds__(256) void prep_kernel(const float* __restrict__ w_off,
                                                   const float* __restrict__ w_dcn,
                                                   const float* __restrict__ w_up,
                                                   u16* __restrict__ Boff,
                                                   u16* __restrict__ Bdcn,
                                                   u16* __restrict__ Bup){
  int i = blockIdx.x * 256 + threadIdx.x;
  if (i < 72*2*64*8){
    int j = i & 7, lane = (i >> 3) & 63, nt = (i >> 9) & 1, kc = i >> 10;
    int n = nt*16 + (lane & 15);
    int k = kc*32 + ((lane >> 4) & 3)*8 + j, tap = k >> 8, c = k & 255;
    int ky = tap / 3, kx = tap - ky*3;
    u16 v = 0;
    if (n < 27) v = f2b(w_off[((n*256 + c)*3 + ky)*3 + kx]);
    Boff[i] = v;
  }
  if (i < 72*8*64*8){
    int j = i & 7, lane = (i >> 3) & 63, nt = (i >> 9) & 7, kc = i >> 12;
    int o = nt*16 + (lane & 15);
    int k = kc*32 + ((lane >> 4) & 3)*8 + j, tap = k >> 8, c = k & 255;
    int ky = tap / 3, kx = tap - ky*3;
    Bdcn[i] = f2b(w_dcn[((o*256 + c)*3 + ky)*3 + kx]);
  }
  if (i < 4*32*4*2*32*8){
    int j = i & 7, n = (i >> 3) & 31, kh = (i >> 8) & 1, a4 = (i >> 9) & 3;
    int kc = (i >> 11) & 31, pp = i >> 16;
    int k = kc*16 + kh*8 + j, tapd = k >> 7, c = k & 127;
    int o = a4*32 + n;
    int py = pp >> 1, px = pp & 1, dy = tapd >> 1, dx = tapd & 1;
    Bup[i] = f2b(w_up[((c*128 + o)*4 + (3-(py+2*dy)))*4 + (3-(px+2*dx))]);
  }
}

// ---------------- x NCHW f32 -> NHWC bf16 ----------------
__global__ __launch_bounds__(256) void transpose_kernel(const float* __restrict__ x, u16* __restrict__ xt){
  __shared__ u16 Ls[64][65];
  int blk = blockIdx.x;                 // 1024 = 4b * 64h * 4cb
  int cb = blk & 3, h = (blk >> 2) & 63, b = blk >> 8;
  int t = threadIdx.x;
  int c0 = cb * 64;
  for (int i = 0; i < 16; i++){
    int idx = t + i*256;
    int c = idx >> 6, w = idx & 63;
    Ls[c][w] = f2b(x[((b*256 + c0 + c)*64 + h)*64 + w]);
  }
  __syncthreads();
  for (int i = 0; i < 16; i++){
    int idx = t + i*256;
    int w = idx >> 6, cc = idx & 63;
    xt[(((b*64 + h)*64 + w) << 8) + c0 + cc] = Ls[cc][w];
  }
}

// ---------------- stage 1: offset conv; dbuf 3-phase pipeline, 4-wave K-split ----------------
__global__ __launch_bounds__(256, 8) void convoff_kernel(const u16* __restrict__ xt,
                                                         const u16* __restrict__ Boff,
                                                         const float* __restrict__ b_off,
                                                         float* __restrict__ om){
  __shared__ alignas(16) char smem[16896];    // As dbuf 2x[16px][264]; Ys overlays
  u16* As0 = (u16*)smem;
  u16* As1 = (u16*)(smem + 8448);
  float* Ys = (float*)smem;                   // [4][16][36] = 9216 B (after final barrier)
  int blk = blockIdx.x;                 // 1024 = 4b * 64h * 4wt
  int wt = blk & 3, h = (blk >> 2) & 63, b = blk >> 8;
  int w0 = wt * 16;
  int P0 = (b*64 + h)*64 + w0;
  int t = threadIdx.x;
  int wv = t >> 6, lane = t & 63;
  int ln = lane & 15, q4 = (lane >> 4) & 3;
  int spx = t >> 5, sc16a = t & 31;     // staging: px = spx(+8), c16
  f32x4 acc[2];
  acc[0] = (f32x4){0.f,0.f,0.f,0.f};
  acc[1] = (f32x4){0.f,0.f,0.f,0.f};
  uint4 pf[2];

  // prefetch + stage tap 0
  {
    int ky = -1, kx = -1;
    #pragma unroll
    for (int it = 0; it < 2; it++){
      int px = spx + it*8;
      int y = h + ky, xw = w0 + px + kx;
      pf[it] = make_uint4(0,0,0,0);
      if ((u32)y < 64u && (u32)xw < 64u)
        pf[it] = *(const uint4*)(xt + (((b*64 + y)*64 + xw) << 8) + sc16a*8);
    }
    #pragma unroll
    for (int it = 0; it < 2; it++)
      *(uint4*)(As0 + (spx + it*8)*264 + sc16a*8) = pf[it];
  }
  __syncthreads();

  for (int tap = 0; tap < 9; tap++){
    const u16* cur = (tap & 1) ? As1 : As0;
    u16* nxt = (tap & 1) ? As0 : As1;
    if (tap < 8){
      int tn = tap + 1;
      int ky = tn/3 - 1, kx = tn - (tn/3)*3 - 1;
      #pragma unroll
      for (int it = 0; it < 2; it++){
        int px = spx + it*8;
        int y = h + ky, xw = w0 + px + kx;
        pf[it] = make_uint4(0,0,0,0);
        if ((u32)y < 64u && (u32)xw < 64u)
          pf[it] = *(const uint4*)(xt + (((b*64 + y)*64 + xw) << 8) + sc16a*8);
      }
    }
    #pragma unroll
    for (int q = 0; q < 2; q++){
      int kcl = wv*2 + q;
      int kcg = tap*8 + kcl;
      short8 a = *(const short8*)(cur + ln*264 + kcl*32 + q4*8);
      #pragma unroll
      for (int nt = 0; nt < 2; nt++){
        short8 bb = *(const short8*)(Boff + ((kcg*2 + nt)*64 + lane)*8);
        acc[nt] = mfma16(a, bb, acc[nt]);
      }
    }
    if (tap < 8){
      #pragma unroll
      for (int it = 0; it < 2; it++)
        *(uint4*)(nxt + (spx + it*8)*264 + sc16a*8) = pf[it];
    }
    __syncthreads();
  }
  // K-split reduction (Ys overlays As; loop's final barrier protects)
  #pragma unroll
  for (int nt = 0; nt < 2; nt++)
    #pragma unroll
    for (int r = 0; r < 4; r++)
      Ys[(wv*16 + q4*4 + r)*36 + nt*16 + ln] = acc[nt][r];
  __syncthreads();
  {
    int px = t >> 4, s = t & 15;
    #pragma unroll
    for (int half = 0; half < 2; half++){
      int n = s + half*16;
      if (n < 27){
        float sum = Ys[(px)*36 + n] + Ys[(16 + px)*36 + n]
                  + Ys[(32 + px)*36 + n] + Ys[(48 + px)*36 + n] + b_off[n];
        om[(P0 + px)*32 + n] = sum;
      }
    }
  }
}

// ---------------- stage 2: mdcn v11 ----------------
// Param table: per (px,tap) 4 clamped corner addresses + 4 mask-folded weights
// (invalid corner -> weight 0, address clamped in-bounds). Hot loop: no bounds
// logic, no exp/floor, no cross-lane shuffles (in-lane 4-corner blend, each
// half-wave owns a pixel). B-fragments prefetched 2-deep in registers.
__global__ __launch_bounds__(256, 4) void mdcn_kernel(const u16* __restrict__ xt,
                                                      const float* __restrict__ om,
                                                      const u16* __restrict__ Bdcn,
                                                      const float* __restrict__ b_dcn,
                                                      u16* __restrict__ yb){
  __shared__ alignas(16) char smem[21504];    // As dbuf 2x8448 | Ptab 4608 (offset 16896)
  u16* As0 = (u16*)smem;
  u16* As1 = (u16*)(smem + 8448);
  float* Ptab = (float*)(smem + 16896);       // [16 px][9 tap][8]: a00,a01,a10,a11,w00,w01,w10,w11
  u16* Lp = (u16*)(smem + 8448);              // [16][136] epilogue overlay of As1
  int blk = blockIdx.x;                 // 1024 = 4b * 64h * 4wt
  int wt = blk & 3, h = (blk >> 2) & 63, b = blk >> 8;
  int w0 = wt * 16;
  int P0 = (b*64 + h)*64 + w0;
  int t = threadIdx.x;
  int wv = t >> 6, lane = t & 63;
  int m = lane & 31, kh = lane >> 5;
  int ln = lane & 15, q4 = (lane >> 4) & 3;
  float bias0 = b_dcn[wv*32 + ln];
  float bias1 = b_dcn[wv*32 + 16 + ln];

  // ---- build param table (one thread per (px,tap)) ----
  if (t < 144){
    int px = t / 9, tap = t - (t/9)*9;
    int ky = tap / 3, kx = tap - ky*3;
    const float* omp = om + (P0 + px)*32;
    float dy  = omp[2*tap];
    float dxv = omp[2*tap + 1];
    float mk  = 1.f / (1.f + __expf(-omp[18 + tap]));
    float ys = (float)(h - 1 + ky) + dy;
    float xs = (float)(w0 + px - 1 + kx) + dxv;
    float y0f = floorf(ys), x0f = floorf(xs);
    float ly = ys - y0f, lx = xs - x0f;
    int y0 = (int)y0f, x0 = (int)x0f;
    bool vy0 = (u32)y0 < 64u, vy1 = (u32)(y0+1) < 64u;
    bool vx0 = (u32)x0 < 64u, vx1 = (u32)(x0+1) < 64u;
    int ya = min(max(y0, 0), 63),   ybr_ = min(max(y0+1, 0), 63);
    int xa = min(max(x0, 0), 63),   xb = min(max(x0+1, 0), 63);
    u32 a00 = (u32)(((b*64 + ya)*64 + xa) << 8);
    u32 a01 = (u32)(((b*64 + ya)*64 + xb) << 8);
    u32 a10 = (u32)(((b*64 + ybr_)*64 + xa) << 8);
    u32 a11 = (u32)(((b*64 + ybr_)*64 + xb) << 8);
    float w00 = (vy0 && vx0) ? (1.f-ly)*(1.f-lx)*mk : 0.f;
    float w01 = (vy0 && vx1) ? (1.f-ly)*lx*mk       : 0.f;
    float w10 = (vy1 && vx0) ? ly*(1.f-lx)*mk       : 0.f;
    float w11 = (vy1 && vx1) ? ly*lx*mk             : 0.f;
    float* P = Ptab + t*8;
    ((u32*)P)[0] = a00; ((u32*)P)[1] = a01; ((u32*)P)[2] = a10; ((u32*)P)[3] = a11;
    P[4] = w00; P[5] = w01; P[6] = w10; P[7] = w11;
  }
  __syncthreads();

  f32x4 acc[2];
  acc[0] = (f32x4){0.f,0.f,0.f,0.f};
  acc[1] = (f32x4){0.f,0.f,0.f,0.f};
  uint4 pu[8];          // 2 iterations x 4 corners
  float4 pwv[2];

  auto prefetch = [&](int tap){
    #pragma unroll
    for (int i = 0; i < 2; i++){
      int p = wv*4 + i*2 + kh;          // this lane's pixel
      const float* P = Ptab + (p*9 + tap)*8;
      uint4 pa = *(const uint4*)P;
      pwv[i] = *(const float4*)(P + 4);
      pu[i*4+0] = *(const uint4*)(xt + pa.x + m*8);
      pu[i*4+1] = *(const uint4*)(xt + pa.y + m*8);
      pu[i*4+2] = *(const uint4*)(xt + pa.z + m*8);
      pu[i*4+3] = *(const uint4*)(xt + pa.w + m*8);
    }
  };
  auto blend_write = [&](u16* dst){
    #pragma unroll
    for (int i = 0; i < 2; i++){
      int p = wv*4 + i*2 + kh;
      float f00[8], f01[8], f10[8], f11[8], s[8];
      unpk(pu[i*4+0], f00); unpk(pu[i*4+1], f01);
      unpk(pu[i*4+2], f10); unpk(pu[i*4+3], f11);
      float4 w = pwv[i];
      #pragma unroll
      for (int j = 0; j < 8; j++)
        s[j] = w.x*f00[j] + w.y*f01[j] + w.z*f10[j] + w.w*f11[j];
      *(uint4*)(dst + p*264 + m*8) = pk8(s);
    }
  };

  prefetch(0);
  blend_write(As0);
  __syncthreads();

  for (int tap = 0; tap < 9; tap++){
    const u16* cur = (tap & 1) ? As1 : As0;
    u16* nxt = (tap & 1) ? As0 : As1;
    if (tap < 8) prefetch(tap + 1);
    // MFMA with 2-deep B prefetch
    {
      int nt0 = wv*2, nt1 = wv*2 + 1;
      int kcg0 = tap*8;
      short8 b0n = *(const short8*)(Bdcn + ((kcg0*8 + nt0)*64 + lane)*8);
      short8 b1n = *(const short8*)(Bdcn + ((kcg0*8 + nt1)*64 + lane)*8);
      #pragma unroll
      for (int kc = 0; kc < 8; kc++){
        short8 b0 = b0n, b1 = b1n;
        if (kc < 7){
          int kcg = tap*8 + kc + 1;
          b0n = *(const short8*)(Bdcn + ((kcg*8 + nt0)*64 + lane)*8);
          b1n = *(const short8*)(Bdcn + ((kcg*8 + nt1)*64 + lane)*8);
        }
        short8 a = *(const short8*)(cur + ln*264 + kc*32 + q4*8);
        acc[0] = mfma16(a, b0, acc[0]);
        acc[1] = mfma16(a, b1, acc[1]);
      }
    }
    if (tap < 8) blend_write(nxt);
    __syncthreads();
  }
  // epilogue: pack 16px x 32ch (this wave) via LDS, coalesced NHWC store
  #pragma unroll
  for (int nt2 = 0; nt2 < 2; nt2++){
    int ch = wv*32 + nt2*16 + ln;
    float bias = nt2 ? bias1 : bias0;
    #pragma unroll
    for (int r = 0; r < 4; r++){
      int px = q4*4 + r;
      Lp[px*136 + ch] = (u16)(rne(acc[nt2][r] + bias) >> 16);
    }
  }
  __syncthreads();
  {
    int px = t >> 4, cg = t & 15;
    uint4 u = *(const uint4*)(Lp + px*136 + cg*8);
    *(uint4*)(yb + (P0 + px)*128 + cg*8) = u;
  }
}

// ---------------- BN1 stats: per-channel sum/sumsq over NHWC bf16 ----------------
__global__ __launch_bounds__(256) void bnstats_kernel(const u16* __restrict__ src,
                                                      float* __restrict__ st, int npix){
  __shared__ float red[256];
  int t = threadIdx.x;
  int ch = t & 127, half = t >> 7;
  float s = 0.f, ss = 0.f;
  for (int p = blockIdx.x*2 + half; p < npix; p += gridDim.x*2){
    float v = b2f(src[p*128 + ch]);
    s += v; ss += v*v;
  }
  red[t] = s; __syncthreads();
  if (t < 128) atomicAdd(&st[t], red[t] + red[t+128]);
  __syncthreads();
  red[t] = ss; __syncthreads();
  if (t < 128) atomicAdd(&st[128 + t], red[t] + red[t+128]);
}

// ---------------- BN2 stats: per-channel over NCHW bf16 (no atomics) ----------------
__global__ __launch_bounds__(256) void bnstats_nchw_kernel(const u16* __restrict__ y2n,
                                                           float* __restrict__ st){
  __shared__ float red[8];
  int ch = blockIdx.x;                  // 128
  int t = threadIdx.x;
  int wv = t >> 6, lane = t & 63;
  float s = 0.f, ss = 0.f;
  for (int b = 0; b < 4; b++){
    const u16* base = y2n + (((b*128 + ch) << 14)) + t*8;
    #pragma unroll
    for (int it = 0; it < 8; it++){
      uint4 u = *(const uint4*)(base + it*2048);
      float f[8]; unpk(u, f);
      #pragma unroll
      for (int e = 0; e < 8; e++){ s += f[e]; ss += f[e]*f[e]; }
    }
  }
  #pragma unroll
  for (int o = 32; o >= 1; o >>= 1){
    s  += __shfl_xor(s, o);
    ss += __shfl_xor(ss, o);
  }
  if (lane == 0){ red[wv*2] = s; red[wv*2+1] = ss; }
  __syncthreads();
  if (t == 0) st[ch]       = red[0] + red[2] + red[4] + red[6];
  if (t == 1) st[128 + ch] = red[1] + red[3] + red[5] + red[7];
}

// ---------------- stage 4: deconv; bn1 finalize in-block (fused), NCHW bf16 out ----------------
__global__ __launch_bounds__(256, 6) void deconv_kernel(const u16* __restrict__ yb,
                                                        const float* __restrict__ stats1,
                                                        const float* __restrict__ gamma1,
                                                        const float* __restrict__ beta1,
                                                        const u16* __restrict__ Bup,
                                                        u16* __restrict__ y2n){
  __shared__ alignas(16) char smem[19520];    // Ls [2][34][136] u16 (18496) | Lo [64][136] overlay; bnL 1024
  u16* Ls = (u16*)smem;
  u16* Lo = (u16*)smem;
  float2* bnL = (float2*)(smem + 18496);
  int blk = blockIdx.x;                 // 1024 = 4b * 128yy * 2half
  int half = blk & 1, yy = (blk >> 1) & 127, b = blk >> 8;
  int pary = yy & 1;
  int hs = (yy - 2 + pary) >> 1;
  int X0 = half * 64, wbase = half*32 - 1;
  int t = threadIdx.x;
  if (t < 128){
    float mean = stats1[t] * (1.f/16384.f);
    float var  = stats1[128 + t] * (1.f/16384.f) - mean*mean;
    float inv  = rsqrtf(var + 1e-5f);
    float sc   = gamma1[t] * inv;
    bnL[t] = make_float2(sc, beta1[t] - mean * sc);
  }
  __syncthreads();
  // stage 2 rows x 34 cols x 128 ch, bn1+relu fused
  #pragma unroll
  for (int it = 0; it < 5; it++){
    int idx = it*256 + t;
    if (idx < 1088){
      int r = idx / 544, rem = idx - r*544;
      int cc = rem >> 4, c16 = rem & 15;
      int hh = hs + r, w_in = wbase + cc;
      uint4 u = make_uint4(0,0,0,0);
      if ((u32)hh < 64u && (u32)w_in < 64u)
        u = *(const uint4*)(yb + (((b*64 + hh)*64 + w_in) << 7) + c16*8);
      float f[8]; unpk(u, f);
      float o[8];
      #pragma unroll
      for (int e = 0; e < 8; e++){
        float2 sc = bnL[c16*8 + e];
        o[e] = fmaxf(0.f, fmaf(sc.x, f[e], sc.y));
      }
      *(uint4*)(Ls + (r*34 + cc)*136 + c16*8) = pk8(o);
    }
  }
  __syncthreads();

  int wv = t >> 6, lane = t & 63;
  int m = lane & 31, kh = lane >> 5;
  int parx = wv & 1, nh = wv >> 1;
  int pp = pary*2 + parx;
  f32x16 acc[2];
  acc[0] = (f32x16){0.f};
  acc[1] = (f32x16){0.f};

  #pragma unroll
  for (int tapd = 0; tapd < 4; tapd++){
    int dyy = tapd >> 1, dxx = tapd & 1;
    const u16* lp = Ls + ((dyy*34 + m + parx + dxx)*136);
    #pragma unroll
    for (int q = 0; q < 8; q++){
      short8 a = *(const short8*)(lp + q*16 + kh*8);
      #pragma unroll
      for (int nt2 = 0; nt2 < 2; nt2++){
        int a4 = nh*2 + nt2;
        short8 bb = *(const short8*)(Bup + ((((pp*32 + tapd*8 + q)*4 + a4)*2 + kh)*32 + m)*8);
        acc[nt2] = mfma32(a, bb, acc[nt2]);
      }
    }
  }
  __syncthreads();                      // done reading Ls; Lo overlays
  #pragma unroll
  for (int nt2 = 0; nt2 < 2; nt2++){
    int ch = (nh*2 + nt2)*32 + m;
    #pragma unroll
    for (int r = 0; r < 16; r++){
      int mrow = (r & 3) + 8*(r >> 2) + 4*kh;
      int xl = parx + 2*mrow;
      Lo[xl*136 + ch] = (u16)(rne(acc[nt2][r]) >> 16);
    }
  }
  __syncthreads();
  // readout: NCHW bf16, 64B contiguous per thread
  {
    int ch = t >> 1, xh = t & 1;
    u16* gp = y2n + ((b*128 + ch)*128 + yy)*128 + X0 + xh*32;
    #pragma unroll
    for (int g = 0; g < 4; g++){
      u32 r4[4];
      #pragma unroll
      for (int e = 0; e < 4; e++){
        u32 lo = Lo[(xh*32 + g*8 + 2*e)*136 + ch];
        u32 hi = Lo[(xh*32 + g*8 + 2*e + 1)*136 + ch];
        r4[e] = lo | (hi << 16);
      }
      *(uint4*)(gp + g*8) = make_uint4(r4[0], r4[1], r4[2], r4[3]);
    }
  }
}

// ---------------- stage 5: BN2 (finalize in-thread) + ReLU elementwise NCHW, f32 out ----------------
__global__ __launch_bounds__(256) void final_kernel(const u16* __restrict__ y2n,
                                                    const float* __restrict__ stats2,
                                                    const float* __restrict__ gamma2,
                                                    const float* __restrict__ beta2,
                                                    float* __restrict__ outp){
  int gid = blockIdx.x*256 + threadIdx.x;   // 4096 blocks
  int idx = gid * 8;
  int ch = (idx >> 14) & 127;
  float mean = stats2[ch] * (1.f/65536.f);
  float var  = stats2[128 + ch] * (1.f/65536.f) - mean*mean;
  float inv  = rsqrtf(var + 1e-5f);
  float scx  = gamma2[ch] * inv;
  float scy  = beta2[ch] - mean * scx;
  uint4 u = *(const uint4*)(y2n + idx);
  float f[8]; unpk(u, f);
  float4 o0, o1;
  o0.x = fmaxf(0.f, fmaf(scx, f[0], scy));
  o0.y = fmaxf(0.f, fmaf(scx, f[1], scy));
  o0.z = fmaxf(0.f, fmaf(scx, f[2], scy));
  o0.w = fmaxf(0.f, fmaf(scx, f[3], scy));
  o1.x = fmaxf(0.f, fmaf(scx, f[4], scy));
  o1.y = fmaxf(0.f, fmaf(scx, f[5], scy));
  o1.z = fmaxf(0.f, fmaf(scx, f[6], scy));
  o1.w = fmaxf(0.f, fmaf(scx, f[7], scy));
  *(float4*)(outp + idx)     = o0;
  *(float4*)(outp + idx + 4) = o1;
}

extern "C" void kernel_launch(void* const* d_in, const int* in_sizes, int n_in,
                              void* d_out, int out_size, void* d_ws, size_t ws_size,
                              hipStream_t stream) {
  const float* x      = (const float*)d_in[0];
  const float* w_off  = (const float*)d_in[1];
  const float* b_off  = (const float*)d_in[2];
  const float* w_dcn  = (const float*)d_in[3];
  const float* b_dcn  = (const float*)d_in[4];
  const float* gamma1 = (const float*)d_in[5];
  const float* beta1  = (const float*)d_in[6];
  const float* w_up   = (const float*)d_in[7];
  const float* gamma2 = (const float*)d_in[8];
  const float* beta2  = (const float*)d_in[9];

  char* ws = (char*)d_ws;
  u16*   xt    = (u16*)(ws + OFF_XT);
  float* om    = (float*)(ws + OFF_OM);
  u16*   yb    = (u16*)(ws + OFF_Y);
  u16*   y2n   = (u16*)(ws + OFF_Y2);
  u16*   Boff  = (u16*)(ws + OFF_BOFF);
  u16*   Bdcn  = (u16*)(ws + OFF_BDCN);
  u16*   Bup   = (u16*)(ws + OFF_BUP);
  float* stats = (float*)(ws + OFF_STATS);

  (void)hipMemsetAsync(stats, 0, 2048, stream);
  prep_kernel<<<1152, 256, 0, stream>>>(w_off, w_dcn, w_up, Boff, Bdcn, Bup);
  transpose_kernel<<<1024, 256, 0, stream>>>(x, xt);
  convoff_kernel<<<1024, 256, 0, stream>>>(xt, Boff, b_off, om);
  mdcn_kernel<<<1024, 256, 0, stream>>>(xt, om, Bdcn, b_dcn, yb);
  bnstats_kernel<<<256, 256, 0, stream>>>(yb, stats, 16384);
  deconv_kernel<<<1024, 256, 0, stream>>>(yb, stats, gamma1, beta1, Bup, y2n);
  bnstats_nchw_kernel<<<128, 256, 0, stream>>>(y2n, stats + 256);
  final_kernel<<<4096, 256, 0, stream>>>(y2n, stats + 256, gamma2, beta2, (float*)d_out);
}